// Round 1
// baseline (99.115 us; speedup 1.0000x reference)
//
#include <hip/hip_runtime.h>

// PointWarping: B=2, C=3, N=8192. Brute-force K=3 NN + inverse-distance flow interp.
// Round 8: (a) explicit depth-2 software pipeline in the candidate scan — 4
// float4 loads in flight while computing 2-iteration-old data (load->use
// decoupled ~350 issue cycles), targeting the ~50% VALU issue utilization
// implied by 49us vs the ~18.5us pure-issue floor; (b) key packing forced to a
// single v_and_or_b32 via inline asm (mask in SGPR, row in VGPR).
// Structure from round 7: keys-only butterfly merge with ballot-based index
// recovery; queries wave-uniform in SGPRs; candidates split 2-way across wave
// pairs; pre-kernel writes warped points as float4 into d_ws (L2-resident);
// packed keys (25-bit d | 7-bit row); exact epilogue recompute.

#define NPTS   8192
#define BLOCK  256
#define Q      4                  // queries per wave (wave-uniform)
#define QPB    8                  // queries per block (2 wave-pairs x 4)
#define HALF   4096               // candidates per wave (2-way split)
#define KMASK  0xFFFFFF80
#define EPSV   1e-10f

__device__ __forceinline__ float rfl_f32(float x) {
    // readfirstlane is b32: bit-cast, never numeric-convert
    return __int_as_float(__builtin_amdgcn_readfirstlane(__float_as_int(x)));
}

// sorted top-3 stream insert, keys only (3 VALU)
__device__ __forceinline__ void ksort3(float k, float& m0, float& m1, float& m2) {
    m2 = __builtin_amdgcn_fmed3f(k, m1, m2);
    m1 = __builtin_amdgcn_fmed3f(k, m0, m1);
    m0 = fminf(k, m0);
}

// key = (bits(d) & KMASK) | row  in ONE VALU op (1 SGPR + 2 VGPR operands)
__device__ __forceinline__ float pack_key(float d, int jg, int km) {
    int r;
    asm("v_and_or_b32 %0, %1, %2, %3"
        : "=v"(r)
        : "v"(__float_as_int(d)), "s"(km), "v"(jg));
    return __int_as_float(r);
}

// sorted top-3 insert with index tracking (epilogue only)
__device__ __forceinline__ void insert3_idx(float k, int idx,
                                            float& m0, float& m1, float& m2,
                                            int& j0, int& j1, int& j2) {
    const bool c0 = k < m0;
    const bool c1 = k < m1;
    const bool c2 = k < m2;
    ksort3(k, m0, m1, m2);
    j2 = c1 ? j1 : (c2 ? idx : j2);
    j1 = c0 ? j0 : (c1 ? idx : j1);
    j0 = c0 ? idx : j0;
}

// pre-kernel: ws[b*NPTS+n] = float4(x1+f1, 0)
__global__ __launch_bounds__(256)
void warp_points_kernel(const float* __restrict__ xyz1,
                        const float* __restrict__ flow1,
                        float4* __restrict__ ws, int total) {
    const int i = blockIdx.x * 256 + threadIdx.x;
    if (i >= total) return;
    const int b = i / NPTS, n = i - b * NPTS;
    const float* x1 = xyz1 + (size_t)b * 3 * NPTS;
    const float* f1 = flow1 + (size_t)b * 3 * NPTS;
    const float px = x1[0*NPTS + n] + f1[0*NPTS + n];
    const float py = x1[1*NPTS + n] + f1[1*NPTS + n];
    const float pz = x1[2*NPTS + n] + f1[2*NPTS + n];
    ws[i] = make_float4(px, py, pz, 0.0f);
}

// per-candidate compute vs all Q wave-uniform queries
#define BODY(P, JG)                                                    \
    {                                                                  \
        _Pragma("unroll")                                              \
        for (int i = 0; i < Q; ++i) {                                  \
            const float dx = (P).x - qx[i];                            \
            const float dy = (P).y - qy[i];                            \
            const float dz = (P).z - qz[i];                            \
            const float d  = fmaf(dx, dx, fmaf(dy, dy, dz * dz));      \
            const float kk = pack_key(d, (JG), km);                    \
            ksort3(kk, k0[i], k1[i], k2[i]);                           \
        }                                                              \
    }

__global__ __launch_bounds__(BLOCK, 8)
void pointwarp_kernel(const float4* __restrict__ wsp,
                      const float* __restrict__ xyz2,
                      const float* __restrict__ flow1,
                      float* __restrict__ out) {
    __shared__ float s_k[2][2][Q][3];
    __shared__ int   s_i[2][2][Q][3];

    const int tid  = threadIdx.x;
    const int w    = tid >> 6;              // wave in block [0,4)
    const int t    = tid & 63;              // lane
    const int pair = w >> 1;                // query-quad [0,2)
    const int w2   = w & 1;                 // candidate half [0,2)
    const int blocksPerB = NPTS / QPB;      // 1024
    const int b     = blockIdx.x / blocksPerB;
    const int qblk  = (blockIdx.x % blocksPerB) * QPB;
    const int qbase = qblk + pair * Q;

    const float4* cand = wsp + (size_t)b * NPTS;
    const float*  x2   = xyz2 + (size_t)b * 3 * NPTS;
    const float*  f1   = flow1 + (size_t)b * 3 * NPTS;

    // wave-uniform queries -> SGPRs (bit-cast broadcast)
    float qx[Q], qy[Q], qz[Q], k0[Q], k1[Q], k2[Q];
    #pragma unroll
    for (int i = 0; i < Q; ++i) {
        qx[i] = rfl_f32(x2[0*NPTS + qbase + i]);
        qy[i] = rfl_f32(x2[1*NPTS + qbase + i]);
        qz[i] = rfl_f32(x2[2*NPTS + qbase + i]);
        k0[i] = k1[i] = k2[i] = 3e38f;
    }

    // scan this wave's half: 2 candidates/iter, depth-2 pipeline (4 loads in
    // flight over ~2 iterations of compute). Rows 2j,2j+1 <- base[j*128 +{0,64}].
    const float4* base = cand + w2 * HALF + t;
    const int km = KMASK;
    int jga = w2 * (HALF / 64);             // wave-uniform row id base [0,128)
    float4 c0 = base[0];
    float4 c1 = base[64];
    float4 c2 = base[128];
    float4 c3 = base[192];
    #pragma unroll 2
    for (int j = 0; j < HALF / 128 - 2; ++j) {   // 30 steady-state iterations
        const float4 n0 = base[(j + 2) * 128];
        const float4 n1 = base[(j + 2) * 128 + 64];
        BODY(c0, jga)
        BODY(c1, jga + 1)
        c0 = c2; c1 = c3; c2 = n0; c3 = n1;
        jga += 2;
    }
    // peeled tail: rows 60..63 of this half (no further loads, no OOB)
    BODY(c0, jga)
    BODY(c1, jga + 1)
    BODY(c2, jga + 2)
    BODY(c3, jga + 3)

    // save pre-merge per-lane top-3 keys (for index resolution)
    float a0[Q], a1[Q], a2[Q];
    #pragma unroll
    for (int i = 0; i < Q; ++i) { a0[i] = k0[i]; a1[i] = k1[i]; a2[i] = k2[i]; }

    // keys-only butterfly merge: 64 partial top-3 -> wave top-3 (all lanes)
    #pragma unroll
    for (int step = 1; step < 64; step <<= 1) {
        #pragma unroll
        for (int i = 0; i < Q; ++i) {
            const float b0 = __shfl_xor(k0[i], step, 64);
            const float b1 = __shfl_xor(k1[i], step, 64);
            const float b2 = __shfl_xor(k2[i], step, 64);
            ksort3(b0, k0[i], k1[i], k2[i]);
            ksort3(b1, k0[i], k1[i], k2[i]);
            ksort3(b2, k0[i], k1[i], k2[i]);
        }
    }

    // resolve indices: first lane whose pre-merge top-3 contains the final key
    int i0[Q], i1[Q], i2[Q];
    #pragma unroll
    for (int i = 0; i < Q; ++i) {
        {
            const float kf = k0[i];
            const unsigned long long m = __ballot(kf == a0[i] || kf == a1[i] || kf == a2[i]);
            i0[i] = ((__float_as_int(kf) & 0x7F) << 6) | (__ffsll(m) - 1);
        }
        {
            const float kf = k1[i];
            const unsigned long long m = __ballot(kf == a0[i] || kf == a1[i] || kf == a2[i]);
            i1[i] = ((__float_as_int(kf) & 0x7F) << 6) | (__ffsll(m) - 1);
        }
        {
            const float kf = k2[i];
            const unsigned long long m = __ballot(kf == a0[i] || kf == a1[i] || kf == a2[i]);
            i2[i] = ((__float_as_int(kf) & 0x7F) << 6) | (__ffsll(m) - 1);
        }
    }

    // publish wave results (all lanes identical; lane i writes query i)
    #pragma unroll
    for (int i = 0; i < Q; ++i) {
        if (t == i) {
            s_k[pair][w2][i][0] = k0[i]; s_i[pair][w2][i][0] = i0[i];
            s_k[pair][w2][i][1] = k1[i]; s_i[pair][w2][i][1] = i1[i];
            s_k[pair][w2][i][2] = k2[i]; s_i[pair][w2][i][2] = i2[i];
        }
    }
    __syncthreads();

    // one thread per query: merge the two candidate-halves, exact weights, write
    if (tid < QPB) {
        const int u  = tid;
        const int pr = u >> 2, qi = u & 3;
        float m0 = 3e38f, m1 = 3e38f, m2 = 3e38f;
        int   j0 = 0, j1 = 0, j2 = 0;
        #pragma unroll
        for (int wv = 0; wv < 2; ++wv) {
            #pragma unroll
            for (int s = 0; s < 3; ++s) {
                insert3_idx(s_k[pr][wv][qi][s], s_i[pr][wv][qi][s],
                            m0, m1, m2, j0, j1, j2);
            }
        }
        const int n2 = qblk + u;
        const float gx = x2[0*NPTS + n2];
        const float gy = x2[1*NPTS + n2];
        const float gz = x2[2*NPTS + n2];
        float dd[3];
        const int js[3] = {j0, j1, j2};
        #pragma unroll
        for (int s = 0; s < 3; ++s) {
            const float4 p = cand[js[s]];
            const float dx = p.x - gx, dy = p.y - gy, dz = p.z - gz;
            dd[s] = fmaf(dx, dx, fmaf(dy, dy, dz*dz));
        }
        float w0 = 1.0f / fmaxf(sqrtf(dd[0]), EPSV);
        float w1 = 1.0f / fmaxf(sqrtf(dd[1]), EPSV);
        float w2v = 1.0f / fmaxf(sqrtf(dd[2]), EPSV);
        const float ws = w0 + w1 + w2v;
        w0 /= ws; w1 /= ws; w2v /= ws;

        float* o = out + (size_t)b * 3 * NPTS;
        #pragma unroll
        for (int c = 0; c < 3; ++c) {
            const float fl = w0  * f1[c*NPTS + j0]
                           + w1  * f1[c*NPTS + j1]
                           + w2v * f1[c*NPTS + j2];
            o[c*NPTS + n2] = x2[c*NPTS + n2] - fl;
        }
    }
}

extern "C" void kernel_launch(void* const* d_in, const int* in_sizes, int n_in,
                              void* d_out, int out_size, void* d_ws, size_t ws_size,
                              hipStream_t stream) {
    const float* xyz1  = (const float*)d_in[0];
    const float* xyz2  = (const float*)d_in[1];
    const float* flow1 = (const float*)d_in[2];
    float* out = (float*)d_out;
    float4* ws = (float4*)d_ws;

    const int B = in_sizes[0] / (3 * NPTS);       // = 2
    const int total = B * NPTS;
    warp_points_kernel<<<(total + 255) / 256, 256, 0, stream>>>(xyz1, flow1, ws, total);
    const int grid = B * (NPTS / QPB);            // 2048 blocks = 8 per CU
    pointwarp_kernel<<<grid, BLOCK, 0, stream>>>(ws, xyz2, flow1, out);
}

// Round 2
// 97.776 us; speedup vs baseline: 1.0137x; 1.0137x over previous
//
#include <hip/hip_runtime.h>

// PointWarping: B=2, C=3, N=8192. Brute-force K=3 NN + inverse-distance flow interp.
// Round 9: inline-asm software pipeline. r8 post-mortem: VGPR_Count=24 proved the
// compiler deleted the source-level pipeline (sank loads to uses -> exposed L2
// latency ~2/3 of runtime). Now candidate loads are issued with raw
// global_load_dwordx4 asm (compiler cannot sink them), 4 pair-buffers = 8 loads
// in flight, manual counted s_waitcnt vmcnt(6) per pair; waited buffers are
// "+v" operands of the wait-asm so all consumers are data-dependent on it.
// vmcnt(0) drain before the prologue; no compiler VMEM inside the loop.
// Structure from round 7: keys-only butterfly merge with ballot index recovery;
// wave-uniform queries in SGPRs; candidates split 2-way across wave pairs;
// pre-kernel writes warped points as float4 into d_ws (L2-resident); packed
// keys (25-bit d | 7-bit row); exact epilogue recompute.

#define NPTS   8192
#define BLOCK  256
#define Q      4                  // queries per wave (wave-uniform)
#define QPB    8                  // queries per block (2 wave-pairs x 4)
#define HALF   4096               // candidates per wave (2-way split)
#define KMASK  0xFFFFFF80
#define EPSV   1e-10f

typedef float f32x4 __attribute__((ext_vector_type(4)));

__device__ __forceinline__ float rfl_f32(float x) {
    // readfirstlane is b32: bit-cast, never numeric-convert
    return __int_as_float(__builtin_amdgcn_readfirstlane(__float_as_int(x)));
}

// sorted top-3 stream insert, keys only (3 VALU)
__device__ __forceinline__ void ksort3(float k, float& m0, float& m1, float& m2) {
    m2 = __builtin_amdgcn_fmed3f(k, m1, m2);
    m1 = __builtin_amdgcn_fmed3f(k, m0, m1);
    m0 = fminf(k, m0);
}

// key = (bits(d) & KMASK) | row  in ONE VALU op (1 SGPR + 2 VGPR operands)
__device__ __forceinline__ float pack_key(float d, int jg, int km) {
    int r;
    asm("v_and_or_b32 %0, %1, %2, %3"
        : "=v"(r)
        : "v"(__float_as_int(d)), "s"(km), "v"(jg));
    return __int_as_float(r);
}

// sorted top-3 insert with index tracking (epilogue only)
__device__ __forceinline__ void insert3_idx(float k, int idx,
                                            float& m0, float& m1, float& m2,
                                            int& j0, int& j1, int& j2) {
    const bool c0 = k < m0;
    const bool c1 = k < m1;
    const bool c2 = k < m2;
    ksort3(k, m0, m1, m2);
    j2 = c1 ? j1 : (c2 ? idx : j2);
    j1 = c0 ? j0 : (c1 ? idx : j1);
    j0 = c0 ? idx : j0;
}

// pre-kernel: ws[b*NPTS+n] = float4(x1+f1, 0)
__global__ __launch_bounds__(256)
void warp_points_kernel(const float* __restrict__ xyz1,
                        const float* __restrict__ flow1,
                        float4* __restrict__ ws, int total) {
    const int i = blockIdx.x * 256 + threadIdx.x;
    if (i >= total) return;
    const int b = i / NPTS, n = i - b * NPTS;
    const float* x1 = xyz1 + (size_t)b * 3 * NPTS;
    const float* f1 = flow1 + (size_t)b * 3 * NPTS;
    const float px = x1[0*NPTS + n] + f1[0*NPTS + n];
    const float py = x1[1*NPTS + n] + f1[1*NPTS + n];
    const float pz = x1[2*NPTS + n] + f1[2*NPTS + n];
    ws[i] = make_float4(px, py, pz, 0.0f);
}

// per-candidate compute vs all Q wave-uniform queries (P is f32x4)
#define BODY(P, JG)                                                    \
    {                                                                  \
        _Pragma("unroll")                                              \
        for (int i = 0; i < Q; ++i) {                                  \
            const float dx = (P)[0] - qx[i];                           \
            const float dy = (P)[1] - qy[i];                           \
            const float dz = (P)[2] - qz[i];                           \
            const float d  = fmaf(dx, dx, fmaf(dy, dy, dz * dz));      \
            const float kk = pack_key(d, (JG), km);                    \
            ksort3(kk, k0[i], k1[i], k2[i]);                           \
        }                                                              \
    }

// issue one candidate pair (rows at byte offsets vo, vo+1024); vo advances 2048
#define ISSUE(B0, B1)                                                  \
    do {                                                               \
        asm volatile("global_load_dwordx4 %0, %2, %3\n\t"              \
                     "global_load_dwordx4 %1, %2, %3 offset:1024"      \
                     : "=&v"(B0), "=&v"(B1)                            \
                     : "v"(vo), "s"(cand));                            \
        vo += 2048u;                                                   \
    } while (0)

// counted wait; waited buffers become outputs so consumers data-depend on it
#define WAITC(N, B0, B1)                                               \
    asm volatile("s_waitcnt vmcnt(" #N ")" : "+v"(B0), "+v"(B1))

__global__ __launch_bounds__(BLOCK, 4)
void pointwarp_kernel(const float4* __restrict__ wsp,
                      const float* __restrict__ xyz2,
                      const float* __restrict__ flow1,
                      float* __restrict__ out) {
    __shared__ float s_k[2][2][Q][3];
    __shared__ int   s_i[2][2][Q][3];

    const int tid  = threadIdx.x;
    const int w    = tid >> 6;              // wave in block [0,4)
    const int t    = tid & 63;              // lane
    const int pair = w >> 1;                // query-quad [0,2)
    const int w2   = w & 1;                 // candidate half [0,2)
    const int blocksPerB = NPTS / QPB;      // 1024
    const int b     = blockIdx.x / blocksPerB;
    const int qblk  = (blockIdx.x % blocksPerB) * QPB;
    const int qbase = qblk + pair * Q;

    const float4* cand = wsp + (size_t)b * NPTS;
    const float*  x2   = xyz2 + (size_t)b * 3 * NPTS;
    const float*  f1   = flow1 + (size_t)b * 3 * NPTS;

    // wave-uniform queries -> SGPRs (bit-cast broadcast)
    float qx[Q], qy[Q], qz[Q], k0[Q], k1[Q], k2[Q];
    #pragma unroll
    for (int i = 0; i < Q; ++i) {
        qx[i] = rfl_f32(x2[0*NPTS + qbase + i]);
        qy[i] = rfl_f32(x2[1*NPTS + qbase + i]);
        qz[i] = rfl_f32(x2[2*NPTS + qbase + i]);
        k0[i] = k1[i] = k2[i] = 3e38f;
    }

    // ---- inline-asm pipelined scan of this wave's half ----
    // 32 pairs of rows; 4 pair-buffers round-robin; 8 loads in flight.
    const int km = KMASK;
    uint32_t vo = (uint32_t)(w2 * (HALF * 16)) + (uint32_t)t * 16u;
    int jga = w2 * (HALF / 64);             // wave-uniform row id base [0,128)

    f32x4 e0, e1, fa0, fa1, g0, g1, h0, h1;

    // clean vmcnt state: drain all compiler-issued loads first
    asm volatile("s_waitcnt vmcnt(0)" ::: "memory");

    ISSUE(e0, e1);
    ISSUE(fa0, fa1);
    ISSUE(g0, g1);
    ISSUE(h0, h1);

    for (int jj = 0; jj < 7; ++jj) {        // computes pairs 0..27, issues 4..31
        WAITC(6, e0, e1);
        BODY(e0, jga) BODY(e1, jga + 1) jga += 2;
        ISSUE(e0, e1);
        WAITC(6, fa0, fa1);
        BODY(fa0, jga) BODY(fa1, jga + 1) jga += 2;
        ISSUE(fa0, fa1);
        WAITC(6, g0, g1);
        BODY(g0, jga) BODY(g1, jga + 1) jga += 2;
        ISSUE(g0, g1);
        WAITC(6, h0, h1);
        BODY(h0, jga) BODY(h1, jga + 1) jga += 2;
        ISSUE(h0, h1);
    }
    // tail: pairs 28..31, draining the queue
    WAITC(6, e0, e1);
    BODY(e0, jga) BODY(e1, jga + 1) jga += 2;
    WAITC(4, fa0, fa1);
    BODY(fa0, jga) BODY(fa1, jga + 1) jga += 2;
    WAITC(2, g0, g1);
    BODY(g0, jga) BODY(g1, jga + 1) jga += 2;
    WAITC(0, h0, h1);
    BODY(h0, jga) BODY(h1, jga + 1) jga += 2;

    // save pre-merge per-lane top-3 keys (for index resolution)
    float a0[Q], a1[Q], a2[Q];
    #pragma unroll
    for (int i = 0; i < Q; ++i) { a0[i] = k0[i]; a1[i] = k1[i]; a2[i] = k2[i]; }

    // keys-only butterfly merge: 64 partial top-3 -> wave top-3 (all lanes)
    #pragma unroll
    for (int step = 1; step < 64; step <<= 1) {
        #pragma unroll
        for (int i = 0; i < Q; ++i) {
            const float b0 = __shfl_xor(k0[i], step, 64);
            const float b1 = __shfl_xor(k1[i], step, 64);
            const float b2 = __shfl_xor(k2[i], step, 64);
            ksort3(b0, k0[i], k1[i], k2[i]);
            ksort3(b1, k0[i], k1[i], k2[i]);
            ksort3(b2, k0[i], k1[i], k2[i]);
        }
    }

    // resolve indices: first lane whose pre-merge top-3 contains the final key
    int i0[Q], i1[Q], i2[Q];
    #pragma unroll
    for (int i = 0; i < Q; ++i) {
        {
            const float kf = k0[i];
            const unsigned long long m = __ballot(kf == a0[i] || kf == a1[i] || kf == a2[i]);
            i0[i] = ((__float_as_int(kf) & 0x7F) << 6) | (__ffsll(m) - 1);
        }
        {
            const float kf = k1[i];
            const unsigned long long m = __ballot(kf == a0[i] || kf == a1[i] || kf == a2[i]);
            i1[i] = ((__float_as_int(kf) & 0x7F) << 6) | (__ffsll(m) - 1);
        }
        {
            const float kf = k2[i];
            const unsigned long long m = __ballot(kf == a0[i] || kf == a1[i] || kf == a2[i]);
            i2[i] = ((__float_as_int(kf) & 0x7F) << 6) | (__ffsll(m) - 1);
        }
    }

    // publish wave results (all lanes identical; lane i writes query i)
    #pragma unroll
    for (int i = 0; i < Q; ++i) {
        if (t == i) {
            s_k[pair][w2][i][0] = k0[i]; s_i[pair][w2][i][0] = i0[i];
            s_k[pair][w2][i][1] = k1[i]; s_i[pair][w2][i][1] = i1[i];
            s_k[pair][w2][i][2] = k2[i]; s_i[pair][w2][i][2] = i2[i];
        }
    }
    __syncthreads();

    // one thread per query: merge the two candidate-halves, exact weights, write
    if (tid < QPB) {
        const int u  = tid;
        const int pr = u >> 2, qi = u & 3;
        float m0 = 3e38f, m1 = 3e38f, m2 = 3e38f;
        int   j0 = 0, j1 = 0, j2 = 0;
        #pragma unroll
        for (int wv = 0; wv < 2; ++wv) {
            #pragma unroll
            for (int s = 0; s < 3; ++s) {
                insert3_idx(s_k[pr][wv][qi][s], s_i[pr][wv][qi][s],
                            m0, m1, m2, j0, j1, j2);
            }
        }
        const int n2 = qblk + u;
        const float gx = x2[0*NPTS + n2];
        const float gy = x2[1*NPTS + n2];
        const float gz = x2[2*NPTS + n2];
        float dd[3];
        const int js[3] = {j0, j1, j2};
        #pragma unroll
        for (int s = 0; s < 3; ++s) {
            const float4 p = cand[js[s]];
            const float dx = p.x - gx, dy = p.y - gy, dz = p.z - gz;
            dd[s] = fmaf(dx, dx, fmaf(dy, dy, dz*dz));
        }
        float w0 = 1.0f / fmaxf(sqrtf(dd[0]), EPSV);
        float w1 = 1.0f / fmaxf(sqrtf(dd[1]), EPSV);
        float w2v = 1.0f / fmaxf(sqrtf(dd[2]), EPSV);
        const float ws = w0 + w1 + w2v;
        w0 /= ws; w1 /= ws; w2v /= ws;

        float* o = out + (size_t)b * 3 * NPTS;
        #pragma unroll
        for (int c = 0; c < 3; ++c) {
            const float fl = w0  * f1[c*NPTS + j0]
                           + w1  * f1[c*NPTS + j1]
                           + w2v * f1[c*NPTS + j2];
            o[c*NPTS + n2] = x2[c*NPTS + n2] - fl;
        }
    }
}

extern "C" void kernel_launch(void* const* d_in, const int* in_sizes, int n_in,
                              void* d_out, int out_size, void* d_ws, size_t ws_size,
                              hipStream_t stream) {
    const float* xyz1  = (const float*)d_in[0];
    const float* xyz2  = (const float*)d_in[1];
    const float* flow1 = (const float*)d_in[2];
    float* out = (float*)d_out;
    float4* ws = (float4*)d_ws;

    const int B = in_sizes[0] / (3 * NPTS);       // = 2
    const int total = B * NPTS;
    warp_points_kernel<<<(total + 255) / 256, 256, 0, stream>>>(xyz1, flow1, ws, total);
    const int grid = B * (NPTS / QPB);            // 2048 blocks = 8 per CU
    pointwarp_kernel<<<grid, BLOCK, 0, stream>>>(ws, xyz2, flow1, out);
}

// Round 3
// 94.358 us; speedup vs baseline: 1.0504x; 1.0362x over previous
//
#include <hip/hip_runtime.h>

// PointWarping: B=2, C=3, N=8192. Brute-force K=3 NN + inverse-distance flow interp.
// Round 10: r9 proved latency is NOT the stall (8-deep asm pipeline, no change).
// Attack instruction count + memory-path contention jointly:
//   (a) |p|^2 precomputed into float4.w -> d = (|p|^2 + q^2) - 2 p.q =
//       1 add + 3 fma (8 VALU/pair vs 10), keys stay at exact d^2 scale;
//   (b) Q=8 queries/wave (QPB=16, 1024 blocks): same total VALU, half the
//       waves and half the L2 candidate traffic; 2 loads per 128 VALU.
// Kept from r9: inline-asm load pipeline (4 pair-buffers, 8 loads in flight,
// counted vmcnt(6), consumers data-dependent on the wait), keys-only butterfly
// merge + ballot index recovery, wave-uniform query constants in SGPRs,
// packed keys (25-bit d | 7-bit row), exact epilogue recompute.

#define NPTS   8192
#define BLOCK  256
#define Q      8                  // queries per wave (wave-uniform)
#define QPB    16                 // queries per block (2 wave-pairs x 8)
#define HALF   4096               // candidates per wave (2-way split)
#define KMASK  0xFFFFFF80
#define EPSV   1e-10f

typedef float f32x4 __attribute__((ext_vector_type(4)));

__device__ __forceinline__ float rfl_f32(float x) {
    // readfirstlane is b32: bit-cast, never numeric-convert
    return __int_as_float(__builtin_amdgcn_readfirstlane(__float_as_int(x)));
}

// sorted top-3 stream insert, keys only (3 VALU)
__device__ __forceinline__ void ksort3(float k, float& m0, float& m1, float& m2) {
    m2 = __builtin_amdgcn_fmed3f(k, m1, m2);
    m1 = __builtin_amdgcn_fmed3f(k, m0, m1);
    m0 = fminf(k, m0);
}

// key = (bits(d) & KMASK) | row  in ONE VALU op (1 SGPR + 2 VGPR operands)
__device__ __forceinline__ float pack_key(float d, int jg, int km) {
    int r;
    asm("v_and_or_b32 %0, %1, %2, %3"
        : "=v"(r)
        : "v"(__float_as_int(d)), "s"(km), "v"(jg));
    return __int_as_float(r);
}

// sorted top-3 insert with index tracking (epilogue only)
__device__ __forceinline__ void insert3_idx(float k, int idx,
                                            float& m0, float& m1, float& m2,
                                            int& j0, int& j1, int& j2) {
    const bool c0 = k < m0;
    const bool c1 = k < m1;
    const bool c2 = k < m2;
    ksort3(k, m0, m1, m2);
    j2 = c1 ? j1 : (c2 ? idx : j2);
    j1 = c0 ? j0 : (c1 ? idx : j1);
    j0 = c0 ? idx : j0;
}

// pre-kernel: ws[b*NPTS+n] = float4(x1+f1, |x1+f1|^2)
__global__ __launch_bounds__(256)
void warp_points_kernel(const float* __restrict__ xyz1,
                        const float* __restrict__ flow1,
                        float4* __restrict__ ws, int total) {
    const int i = blockIdx.x * 256 + threadIdx.x;
    if (i >= total) return;
    const int b = i / NPTS, n = i - b * NPTS;
    const float* x1 = xyz1 + (size_t)b * 3 * NPTS;
    const float* f1 = flow1 + (size_t)b * 3 * NPTS;
    const float px = x1[0*NPTS + n] + f1[0*NPTS + n];
    const float py = x1[1*NPTS + n] + f1[1*NPTS + n];
    const float pz = x1[2*NPTS + n] + f1[2*NPTS + n];
    const float pw = fmaf(px, px, fmaf(py, py, pz * pz));
    ws[i] = make_float4(px, py, pz, pw);
}

// per-candidate compute vs all Q wave-uniform queries (P is f32x4)
// d = (|p|^2 + q^2) - 2 p.q : add + 3 fma + pack + 3 sort = 8 VALU
#define BODY(P, JG)                                                    \
    {                                                                  \
        _Pragma("unroll")                                              \
        for (int i = 0; i < Q; ++i) {                                  \
            const float t0 = (P)[3] + q2[i];                           \
            const float t1 = fmaf(nqz[i], (P)[2], t0);                 \
            const float t2 = fmaf(nqy[i], (P)[1], t1);                 \
            const float d  = fmaf(nqx[i], (P)[0], t2);                 \
            const float kk = pack_key(d, (JG), km);                    \
            ksort3(kk, k0[i], k1[i], k2[i]);                           \
        }                                                              \
    }

// issue one candidate pair (rows at byte offsets vo, vo+1024); vo advances 2048
#define ISSUE(B0, B1)                                                  \
    do {                                                               \
        asm volatile("global_load_dwordx4 %0, %2, %3\n\t"              \
                     "global_load_dwordx4 %1, %2, %3 offset:1024"      \
                     : "=&v"(B0), "=&v"(B1)                            \
                     : "v"(vo), "s"(cand));                            \
        vo += 2048u;                                                   \
    } while (0)

// counted wait; waited buffers become outputs so consumers data-depend on it
#define WAITC(N, B0, B1)                                               \
    asm volatile("s_waitcnt vmcnt(" #N ")" : "+v"(B0), "+v"(B1))

__global__ __launch_bounds__(BLOCK, 4)
void pointwarp_kernel(const float4* __restrict__ wsp,
                      const float* __restrict__ xyz2,
                      const float* __restrict__ flow1,
                      float* __restrict__ out) {
    __shared__ float s_k[2][2][Q][3];
    __shared__ int   s_i[2][2][Q][3];

    const int tid  = threadIdx.x;
    const int w    = tid >> 6;              // wave in block [0,4)
    const int t    = tid & 63;              // lane
    const int pair = w >> 1;                // query-octet [0,2)
    const int w2   = w & 1;                 // candidate half [0,2)
    const int blocksPerB = NPTS / QPB;      // 512
    const int b     = blockIdx.x / blocksPerB;
    const int qblk  = (blockIdx.x % blocksPerB) * QPB;
    const int qbase = qblk + pair * Q;

    const float4* cand = wsp + (size_t)b * NPTS;
    const float*  x2   = xyz2 + (size_t)b * 3 * NPTS;
    const float*  f1   = flow1 + (size_t)b * 3 * NPTS;

    // wave-uniform query constants -> SGPRs: nq = -2*q, q2 = |q|^2
    float nqx[Q], nqy[Q], nqz[Q], q2[Q], k0[Q], k1[Q], k2[Q];
    #pragma unroll
    for (int i = 0; i < Q; ++i) {
        const float x = x2[0*NPTS + qbase + i];
        const float y = x2[1*NPTS + qbase + i];
        const float z = x2[2*NPTS + qbase + i];
        nqx[i] = rfl_f32(-2.0f * x);
        nqy[i] = rfl_f32(-2.0f * y);
        nqz[i] = rfl_f32(-2.0f * z);
        q2[i]  = rfl_f32(fmaf(x, x, fmaf(y, y, z * z)));
        k0[i] = k1[i] = k2[i] = 3e38f;
    }

    // ---- inline-asm pipelined scan of this wave's half ----
    // 32 pairs of rows; 4 pair-buffers round-robin; 8 loads in flight.
    const int km = KMASK;
    uint32_t vo = (uint32_t)(w2 * (HALF * 16)) + (uint32_t)t * 16u;
    int jga = w2 * (HALF / 64);             // wave-uniform row id base [0,128)

    f32x4 e0, e1, fa0, fa1, g0, g1, h0, h1;

    // clean vmcnt state: drain all compiler-issued loads first
    asm volatile("s_waitcnt vmcnt(0)" ::: "memory");

    ISSUE(e0, e1);
    ISSUE(fa0, fa1);
    ISSUE(g0, g1);
    ISSUE(h0, h1);

    for (int jj = 0; jj < 7; ++jj) {        // computes pairs 0..27, issues 4..31
        WAITC(6, e0, e1);
        BODY(e0, jga) BODY(e1, jga + 1) jga += 2;
        ISSUE(e0, e1);
        WAITC(6, fa0, fa1);
        BODY(fa0, jga) BODY(fa1, jga + 1) jga += 2;
        ISSUE(fa0, fa1);
        WAITC(6, g0, g1);
        BODY(g0, jga) BODY(g1, jga + 1) jga += 2;
        ISSUE(g0, g1);
        WAITC(6, h0, h1);
        BODY(h0, jga) BODY(h1, jga + 1) jga += 2;
        ISSUE(h0, h1);
    }
    // tail: pairs 28..31, draining the queue
    WAITC(6, e0, e1);
    BODY(e0, jga) BODY(e1, jga + 1) jga += 2;
    WAITC(4, fa0, fa1);
    BODY(fa0, jga) BODY(fa1, jga + 1) jga += 2;
    WAITC(2, g0, g1);
    BODY(g0, jga) BODY(g1, jga + 1) jga += 2;
    WAITC(0, h0, h1);
    BODY(h0, jga) BODY(h1, jga + 1) jga += 2;

    // save pre-merge per-lane top-3 keys (for index resolution)
    float a0[Q], a1[Q], a2[Q];
    #pragma unroll
    for (int i = 0; i < Q; ++i) { a0[i] = k0[i]; a1[i] = k1[i]; a2[i] = k2[i]; }

    // keys-only butterfly merge: 64 partial top-3 -> wave top-3 (all lanes)
    #pragma unroll
    for (int step = 1; step < 64; step <<= 1) {
        #pragma unroll
        for (int i = 0; i < Q; ++i) {
            const float b0 = __shfl_xor(k0[i], step, 64);
            const float b1 = __shfl_xor(k1[i], step, 64);
            const float b2 = __shfl_xor(k2[i], step, 64);
            ksort3(b0, k0[i], k1[i], k2[i]);
            ksort3(b1, k0[i], k1[i], k2[i]);
            ksort3(b2, k0[i], k1[i], k2[i]);
        }
    }

    // resolve indices: first lane whose pre-merge top-3 contains the final key
    int i0[Q], i1[Q], i2[Q];
    #pragma unroll
    for (int i = 0; i < Q; ++i) {
        {
            const float kf = k0[i];
            const unsigned long long m = __ballot(kf == a0[i] || kf == a1[i] || kf == a2[i]);
            i0[i] = ((__float_as_int(kf) & 0x7F) << 6) | (__ffsll(m) - 1);
        }
        {
            const float kf = k1[i];
            const unsigned long long m = __ballot(kf == a0[i] || kf == a1[i] || kf == a2[i]);
            i1[i] = ((__float_as_int(kf) & 0x7F) << 6) | (__ffsll(m) - 1);
        }
        {
            const float kf = k2[i];
            const unsigned long long m = __ballot(kf == a0[i] || kf == a1[i] || kf == a2[i]);
            i2[i] = ((__float_as_int(kf) & 0x7F) << 6) | (__ffsll(m) - 1);
        }
    }

    // publish wave results (all lanes identical; lane i writes query i)
    #pragma unroll
    for (int i = 0; i < Q; ++i) {
        if (t == i) {
            s_k[pair][w2][i][0] = k0[i]; s_i[pair][w2][i][0] = i0[i];
            s_k[pair][w2][i][1] = k1[i]; s_i[pair][w2][i][1] = i1[i];
            s_k[pair][w2][i][2] = k2[i]; s_i[pair][w2][i][2] = i2[i];
        }
    }
    __syncthreads();

    // one thread per query: merge the two candidate-halves, exact weights, write
    if (tid < QPB) {
        const int u  = tid;
        const int pr = u >> 3, qi = u & 7;
        float m0 = 3e38f, m1 = 3e38f, m2 = 3e38f;
        int   j0 = 0, j1 = 0, j2 = 0;
        #pragma unroll
        for (int wv = 0; wv < 2; ++wv) {
            #pragma unroll
            for (int s = 0; s < 3; ++s) {
                insert3_idx(s_k[pr][wv][qi][s], s_i[pr][wv][qi][s],
                            m0, m1, m2, j0, j1, j2);
            }
        }
        const int n2 = qblk + u;
        const float gx = x2[0*NPTS + n2];
        const float gy = x2[1*NPTS + n2];
        const float gz = x2[2*NPTS + n2];
        float dd[3];
        const int js[3] = {j0, j1, j2};
        #pragma unroll
        for (int s = 0; s < 3; ++s) {
            const float4 p = cand[js[s]];
            const float dx = p.x - gx, dy = p.y - gy, dz = p.z - gz;
            dd[s] = fmaf(dx, dx, fmaf(dy, dy, dz*dz));
        }
        float w0 = 1.0f / fmaxf(sqrtf(dd[0]), EPSV);
        float w1 = 1.0f / fmaxf(sqrtf(dd[1]), EPSV);
        float w2v = 1.0f / fmaxf(sqrtf(dd[2]), EPSV);
        const float ws = w0 + w1 + w2v;
        w0 /= ws; w1 /= ws; w2v /= ws;

        float* o = out + (size_t)b * 3 * NPTS;
        #pragma unroll
        for (int c = 0; c < 3; ++c) {
            const float fl = w0  * f1[c*NPTS + j0]
                           + w1  * f1[c*NPTS + j1]
                           + w2v * f1[c*NPTS + j2];
            o[c*NPTS + n2] = x2[c*NPTS + n2] - fl;
        }
    }
}

extern "C" void kernel_launch(void* const* d_in, const int* in_sizes, int n_in,
                              void* d_out, int out_size, void* d_ws, size_t ws_size,
                              hipStream_t stream) {
    const float* xyz1  = (const float*)d_in[0];
    const float* xyz2  = (const float*)d_in[1];
    const float* flow1 = (const float*)d_in[2];
    float* out = (float*)d_out;
    float4* ws = (float4*)d_ws;

    const int B = in_sizes[0] / (3 * NPTS);       // = 2
    const int total = B * NPTS;
    warp_points_kernel<<<(total + 255) / 256, 256, 0, stream>>>(xyz1, flow1, ws, total);
    const int grid = B * (NPTS / QPB);            // 1024 blocks = 4 per CU
    pointwarp_kernel<<<grid, BLOCK, 0, stream>>>(ws, xyz2, flow1, out);
}